// Round 1
// baseline (687.978 us; speedup 1.0000x reference)
//
#include <hip/hip_runtime.h>

// Correlation / cost-volume (kernel_size=1, stride=1, max_disp=4).
// out[b, dy*9+dx, y, x] = (1/C) * sum_c in1[b,c,y,x] * in2[b,c,y+dy-4,x+dx-4]
// B=8 C=192 H=W=128 fp32. No fp32 MFMA -> vector ALU; LDS-pipe was the
// bottleneck (1 b128 : 12 FMA). This version: XR=8 (1:18), conflict-free
// padded stride 44, double-buffered LDS w/ 1 barrier per 12-ch chunk,
// register-staged async prefetch, batch-per-XCD block swizzle.

constexpr int MAXD = 4;
constexpr int WIN  = 2 * MAXD + 1;      // 9
constexpr int Bn = 8, Cn = 192, Hn = 128, Wn = 128;

constexpr int XT = 32;                  // tile width (outputs)
constexpr int YT = 16;                  // tile height
constexpr int XR = 8;                   // x pixels per thread
constexpr int XG = XT / XR;             // 4 x-groups
constexpr int W2 = XT + 2 * MAXD;       // 40 valid in2 cols
constexpr int H2 = YT + 2 * MAXD;       // 24 in2 rows
constexpr int SP = 44;                  // padded LDS row stride (floats): (12*row+8*tx)%32 distinct per 8 lanes
constexpr int CC = 12;                  // channels per chunk
constexpr int NT = XG * YT * WIN;       // 576 threads = 9 waves (wave id == dy)
constexpr int KPR = W2 / 4;             // 10 float4 per staged row
constexpr int PIECES = CC * H2 * KPR;   // 2880
constexpr int PPT = PIECES / NT;        // 5 (exact)
constexpr int NCHUNK = Cn / CC;         // 16
constexpr int BUF = CC * H2 * SP;       // 12672 floats per buffer

__global__ __launch_bounds__(NT)
void corr_kernel(const float* __restrict__ in1,
                 const float* __restrict__ in2,
                 float* __restrict__ out)
{
    __shared__ float s2[2 * BUF];       // 101,376 B (<=160K/CU, 1 block/CU)

    const int tid = threadIdx.x;
    const int tx  = tid & 3;            // x group (offset tx*8)
    const int ty  = (tid >> 2) & 15;    // y within tile
    const int g   = tid >> 6;           // wave id == dy (0..8)

    // ---- batch-per-XCD swizzle: xcd = flat%8 gets all 32 tiles of batch b ----
    const int fb = blockIdx.x + gridDim.x * (blockIdx.y + gridDim.y * blockIdx.z);
    const int b  = fb & 7;
    const int t  = fb >> 3;             // 0..31
    const int x0 = (t & 3) * XT;
    const int y0 = (t >> 2) * YT;

    const int x = x0 + tx * XR;
    const int y = y0 + ty;

    const float* in2b = in2 + (size_t)b * Cn * Hn * Wn;

    // ---- staging precompute (loop-invariant): 5 pieces per thread ----
    int   soff[PPT];                    // LDS float offset
    int   goff[PPT];                    // global float offset within (b, chunk-base)
    float msk[PPT];                     // 1.0 valid / 0.0 zero-pad (4-aligned => per-float4)
    #pragma unroll
    for (int p = 0; p < PPT; ++p) {
        int piece = tid + p * NT;
        int c   = piece / (H2 * KPR);
        int rem = piece % (H2 * KPR);
        int row = rem / KPR;
        int k   = rem % KPR;
        int gy = y0 - MAXD + row;
        int gx = x0 - MAXD + 4 * k;
        int cy = gy < 0 ? 0 : (gy > Hn - 1 ? Hn - 1 : gy);
        int cx = gx < 0 ? 0 : (gx > Wn - 4 ? Wn - 4 : gx);
        soff[p] = (c * H2 + row) * SP + 4 * k;
        goff[p] = (c * Hn + cy) * Wn + cx;
        msk[p]  = (gy >= 0 && gy < Hn && gx >= 0 && gx <= Wn - 4) ? 1.f : 0.f;
    }

    float acc[WIN][XR];
    #pragma unroll
    for (int dx = 0; dx < WIN; ++dx)
        #pragma unroll
        for (int i = 0; i < XR; ++i) acc[dx][i] = 0.f;

    const float* a_base = in1 + (((size_t)b * Cn) * Hn + y) * Wn + x;

    // ---- prologue: prefetch chunk 0 into registers ----
    float4 r[PPT];
    #pragma unroll
    for (int p = 0; p < PPT; ++p) r[p] = *(const float4*)(in2b + goff[p]);

    #pragma unroll 1
    for (int ci = 0; ci < NCHUNK; ++ci) {
        // write staged regs -> LDS buffer ci&1 (freed by barrier of iter ci-1)
        float* dst = &s2[(ci & 1) * BUF];
        #pragma unroll
        for (int p = 0; p < PPT; ++p) {
            float4 v = r[p];
            float  m = msk[p];
            v.x *= m; v.y *= m; v.z *= m; v.w *= m;
            *(float4*)(dst + soff[p]) = v;
        }
        __syncthreads();   // single barrier per chunk; vmcnt queue is empty here

        // issue next chunk's global loads BEFORE compute (latency hides under FMAs)
        if (ci + 1 < NCHUNK) {
            const float* src = in2b + (size_t)(ci + 1) * CC * Hn * Wn;
            #pragma unroll
            for (int p = 0; p < PPT; ++p) r[p] = *(const float4*)(src + goff[p]);
        }

        // ---- compute 12 channels: per channel 4 ds_read_b128 -> 72 FMA ----
        const float* cur = &s2[(ci & 1) * BUF];
        const float* ap  = a_base + (size_t)ci * CC * Hn * Wn;
        #pragma unroll
        for (int cc = 0; cc < CC; ++cc) {
            float4 a0 = *(const float4*)(ap + (size_t)cc * Hn * Wn);
            float4 a1 = *(const float4*)(ap + (size_t)cc * Hn * Wn + 4);
            const float* rp = cur + (cc * H2 + ty + g) * SP + tx * XR;
            float fv[16];
            *(float4*)&fv[0]  = *(const float4*)(rp);
            *(float4*)&fv[4]  = *(const float4*)(rp + 4);
            *(float4*)&fv[8]  = *(const float4*)(rp + 8);
            *(float4*)&fv[12] = *(const float4*)(rp + 12);
            #pragma unroll
            for (int dx = 0; dx < WIN; ++dx) {
                acc[dx][0] += a0.x * fv[dx + 0];
                acc[dx][1] += a0.y * fv[dx + 1];
                acc[dx][2] += a0.z * fv[dx + 2];
                acc[dx][3] += a0.w * fv[dx + 3];
                acc[dx][4] += a1.x * fv[dx + 4];
                acc[dx][5] += a1.y * fv[dx + 5];
                acc[dx][6] += a1.z * fv[dx + 6];
                acc[dx][7] += a1.w * fv[dx + 7];
            }
        }
    }

    // ---- epilogue ----
    const float sc = 1.0f / (float)Cn;
    float* op = out + (((size_t)b * (WIN * WIN) + g * WIN) * Hn + y) * Wn + x;
    #pragma unroll
    for (int dx = 0; dx < WIN; ++dx) {
        float4 v0 = { acc[dx][0] * sc, acc[dx][1] * sc, acc[dx][2] * sc, acc[dx][3] * sc };
        float4 v1 = { acc[dx][4] * sc, acc[dx][5] * sc, acc[dx][6] * sc, acc[dx][7] * sc };
        *(float4*)(op + (size_t)dx * Hn * Wn)     = v0;
        *(float4*)(op + (size_t)dx * Hn * Wn + 4) = v1;
    }
}

extern "C" void kernel_launch(void* const* d_in, const int* in_sizes, int n_in,
                              void* d_out, int out_size, void* d_ws, size_t ws_size,
                              hipStream_t stream) {
    const float* in1 = (const float*)d_in[0];
    const float* in2 = (const float*)d_in[1];
    float* out = (float*)d_out;
    dim3 grid(Wn / XT, Hn / YT, Bn);   // 4 x 8 x 8 = 256 blocks = 1/CU
    corr_kernel<<<grid, NT, 0, stream>>>(in1, in2, out);
}

// Round 2
// 346.140 us; speedup vs baseline: 1.9876x; 1.9876x over previous
//
#include <hip/hip_runtime.h>

// Correlation / cost-volume (kernel_size=1, stride=1, max_disp=4).
// out[b, dy*9+dx, y, x] = (1/C) * sum_c in1[b,c,y,x] * in2[b,c,y+dy-4,x+dx-4]
// B=8 C=192 H=W=128 fp32. No fp32 MFMA -> vector ALU.
// R1 post-mortem: default regalloc capped VGPR at 84 -> acc[9][8] spilled
// (908 MB scratch writes). Fix: __launch_bounds__(NT,2) raises cap to the
// 576-thread block limit (~168); unroll-4 channel loop bounds transient
// pressure; masks packed into one int. Structure unchanged: XR=8
// (1 ds_read_b128 : 18 FMA), SP=44 conflict-free stride, double-buffered
// LDS, 1 barrier/chunk, register-staged prefetch, batch-per-XCD swizzle.

constexpr int MAXD = 4;
constexpr int WIN  = 2 * MAXD + 1;      // 9
constexpr int Bn = 8, Cn = 192, Hn = 128, Wn = 128;

constexpr int XT = 32;                  // tile width (outputs)
constexpr int YT = 16;                  // tile height
constexpr int XR = 8;                   // x pixels per thread
constexpr int XG = XT / XR;             // 4 x-groups
constexpr int W2 = XT + 2 * MAXD;       // 40 valid in2 cols
constexpr int H2 = YT + 2 * MAXD;       // 24 in2 rows
constexpr int SP = 44;                  // padded LDS row stride (floats)
constexpr int CC = 12;                  // channels per chunk
constexpr int NT = XG * YT * WIN;       // 576 threads = 9 waves (wave id == dy)
constexpr int KPR = W2 / 4;             // 10 float4 per staged row
constexpr int PIECES = CC * H2 * KPR;   // 2880
constexpr int PPT = PIECES / NT;        // 5 (exact)
constexpr int NCHUNK = Cn / CC;         // 16
constexpr int BUF = CC * H2 * SP;       // 12672 floats per buffer

__global__ __launch_bounds__(NT, 2)     // raise VGPR cap (block-size limit ~168)
void corr_kernel(const float* __restrict__ in1,
                 const float* __restrict__ in2,
                 float* __restrict__ out)
{
    __shared__ float s2[2 * BUF];       // 101,376 B -> 1 block/CU

    const int tid = threadIdx.x;
    const int tx  = tid & 3;            // x group (offset tx*8)
    const int ty  = (tid >> 2) & 15;    // y within tile
    const int g   = tid >> 6;           // wave id == dy (0..8)

    // ---- batch-per-XCD swizzle: xcd = flat%8 gets all 32 tiles of batch b ----
    const int fb = blockIdx.x + gridDim.x * (blockIdx.y + gridDim.y * blockIdx.z);
    const int b  = fb & 7;
    const int t  = fb >> 3;             // 0..31
    const int x0 = (t & 3) * XT;
    const int y0 = (t >> 2) * YT;

    const int x = x0 + tx * XR;
    const int y = y0 + ty;

    const float* in2b = in2 + (size_t)b * Cn * Hn * Wn;

    // ---- staging precompute (loop-invariant): 5 pieces per thread ----
    int soff[PPT];                      // LDS float offset
    int goff[PPT];                      // global float offset within chunk base
    int mbits = 0;                      // validity bits (4-aligned => per-float4)
    #pragma unroll
    for (int p = 0; p < PPT; ++p) {
        int piece = tid + p * NT;
        int c   = piece / (H2 * KPR);
        int rem = piece % (H2 * KPR);
        int row = rem / KPR;
        int k   = rem % KPR;
        int gy = y0 - MAXD + row;
        int gx = x0 - MAXD + 4 * k;
        int cy = gy < 0 ? 0 : (gy > Hn - 1 ? Hn - 1 : gy);
        int cx = gx < 0 ? 0 : (gx > Wn - 4 ? Wn - 4 : gx);
        soff[p] = (c * H2 + row) * SP + 4 * k;
        goff[p] = (c * Hn + cy) * Wn + cx;
        if (gy >= 0 && gy < Hn && gx >= 0 && gx <= Wn - 4) mbits |= (1 << p);
    }

    float acc[WIN][XR];
    #pragma unroll
    for (int dx = 0; dx < WIN; ++dx)
        #pragma unroll
        for (int i = 0; i < XR; ++i) acc[dx][i] = 0.f;

    const float* a_base = in1 + (((size_t)b * Cn) * Hn + y) * Wn + x;

    // ---- prologue: prefetch chunk 0 into registers (masked at load) ----
    float4 r[PPT];
    #pragma unroll
    for (int p = 0; p < PPT; ++p) {
        float4 v = *(const float4*)(in2b + goff[p]);
        float  m = (mbits >> p) & 1 ? 1.f : 0.f;
        v.x *= m; v.y *= m; v.z *= m; v.w *= m;
        r[p] = v;
    }

    #pragma unroll 1
    for (int ci = 0; ci < NCHUNK; ++ci) {
        // write staged regs -> LDS buffer ci&1 (freed by barrier of iter ci-1)
        float* dst = &s2[(ci & 1) * BUF];
        #pragma unroll
        for (int p = 0; p < PPT; ++p)
            *(float4*)(dst + soff[p]) = r[p];
        __syncthreads();   // single barrier per chunk; vmcnt queue empty here

        // issue next chunk's global loads BEFORE compute (latency under FMAs)
        if (ci + 1 < NCHUNK) {
            const float* src = in2b + (size_t)(ci + 1) * CC * Hn * Wn;
            #pragma unroll
            for (int p = 0; p < PPT; ++p) {
                float4 v = *(const float4*)(src + goff[p]);
                float  m = (mbits >> p) & 1 ? 1.f : 0.f;
                v.x *= m; v.y *= m; v.z *= m; v.w *= m;
                r[p] = v;
            }
        }

        // ---- compute 12 channels: per channel 4 ds_read_b128 -> 72 FMA ----
        const float* cur = &s2[(ci & 1) * BUF];
        const float* ap  = a_base + (size_t)ci * CC * Hn * Wn;
        #pragma unroll 4               // bound in-flight in1 loads (reg pressure)
        for (int cc = 0; cc < CC; ++cc) {
            float4 a0 = *(const float4*)(ap + (size_t)cc * Hn * Wn);
            float4 a1 = *(const float4*)(ap + (size_t)cc * Hn * Wn + 4);
            const float* rp = cur + (cc * H2 + ty + g) * SP + tx * XR;
            float fv[16];
            *(float4*)&fv[0]  = *(const float4*)(rp);
            *(float4*)&fv[4]  = *(const float4*)(rp + 4);
            *(float4*)&fv[8]  = *(const float4*)(rp + 8);
            *(float4*)&fv[12] = *(const float4*)(rp + 12);
            #pragma unroll
            for (int dx = 0; dx < WIN; ++dx) {
                acc[dx][0] += a0.x * fv[dx + 0];
                acc[dx][1] += a0.y * fv[dx + 1];
                acc[dx][2] += a0.z * fv[dx + 2];
                acc[dx][3] += a0.w * fv[dx + 3];
                acc[dx][4] += a1.x * fv[dx + 4];
                acc[dx][5] += a1.y * fv[dx + 5];
                acc[dx][6] += a1.z * fv[dx + 6];
                acc[dx][7] += a1.w * fv[dx + 7];
            }
        }
    }

    // ---- epilogue ----
    const float sc = 1.0f / (float)Cn;
    float* op = out + (((size_t)b * (WIN * WIN) + g * WIN) * Hn + y) * Wn + x;
    #pragma unroll
    for (int dx = 0; dx < WIN; ++dx) {
        float4 v0 = { acc[dx][0] * sc, acc[dx][1] * sc, acc[dx][2] * sc, acc[dx][3] * sc };
        float4 v1 = { acc[dx][4] * sc, acc[dx][5] * sc, acc[dx][6] * sc, acc[dx][7] * sc };
        *(float4*)(op + (size_t)dx * Hn * Wn)     = v0;
        *(float4*)(op + (size_t)dx * Hn * Wn + 4) = v1;
    }
}

extern "C" void kernel_launch(void* const* d_in, const int* in_sizes, int n_in,
                              void* d_out, int out_size, void* d_ws, size_t ws_size,
                              hipStream_t stream) {
    const float* in1 = (const float*)d_in[0];
    const float* in2 = (const float*)d_in[1];
    float* out = (float*)d_out;
    dim3 grid(Wn / XT, Hn / YT, Bn);   // 4 x 8 x 8 = 256 blocks = 1/CU
    corr_kernel<<<grid, NT, 0, stream>>>(in1, in2, out);
}